// Round 7
// baseline (9295.160 us; speedup 1.0000x reference)
//
#include <hip/hip_runtime.h>
#include <stdint.h>

// LSTM (B=256,T=512,I=512,H=1024) + FC on MI355X.
// Persistent 256-block kernel, 1 block/CU. Block owns (jt: 32 hidden units ->
// 128 gate rows, bt: 32 batch rows). h exchanged via LLC using r2-proven
// idioms: agent-scope relaxed atomic stores (sc0 sc1, land at LLC),
// global_load_lds aux=17 (SC0|SC1, read at LLC), agent-scope relaxed loads.
// ROUND 13: BARRIER-FREE K-REDUCTION. Round-12 counters: occupancy goal met
// (24%, 2 waves/SIMD), weights resident, no spill, MFMA busy time == baseline
// (677 vs 690us) — but wall +830us vs the 4-wave baseline, i.e. pure stall:
// the G1/barrier/G2 partial exchange added a 5th barrier and a zl
// write->read->activate serial segment, and conflicts doubled. This round:
// both k-half waves ds_add_f32 (atomicAdd on __shared__, native LDS f32 add)
// their raw partials into zl — no ordering needed between partner waves —
// and the activation moves into the I-phase (biases in regs, 8 act + 2
// tanh(c) per thread). zl slots are re-zeroed by the unique I-thread that
// read them (slot<->thread bijective, no race; J barrier orders vs next G).
// Step is back to the baseline's 4 barriers: C(poll), E(drain), H, J.
// K-SPLIT ACROSS 8 WAVES (512 threads, 2 waves/SIMD): wave (gate g, half p)
// holds HALF the k-slices (fb[2][24] = 192 regs) -> 2 waves/SIMD cover each
// other's ds_read latency and the poll/store tail. c in fp32 regs. FC fp32.

#define T_STEPS 512

typedef __bf16 bf16x8 __attribute__((ext_vector_type(8)));
typedef float  f32x4  __attribute__((ext_vector_type(4)));
typedef float  f32x2  __attribute__((ext_vector_type(2)));

__device__ __forceinline__ uint16_t f2bf(float f) {
  uint32_t u = __float_as_uint(f);
  u += 0x7fffu + ((u >> 16) & 1u);   // RNE
  return (uint16_t)(u >> 16);
}
__device__ __forceinline__ float sigmoid_f(float z) {
  return 1.0f / (1.0f + __expf(-z));
}
__device__ __forceinline__ float tanh_f(float x) {
  float ax = __builtin_fabsf(x);
  float e  = __expf(-2.0f * ax);
  float r  = (1.0f - e) / (1.0f + e);
  return __builtin_copysignf(r, x);
}

// ws layout (bytes):
//   [0, 12582912)            Wpack  : bf16 frags [jt32][w4][q2][s48][lane64][8]
//   [12582912, +134217728)   xpack  : bf16 frags [t512][bt8][ks16][mt2][lane64][8]
//   [146800640, +1048576)    hpack  : bf16 frags [phase2][bt8][jt32][mt2][lane64][8]
//   [147849216, +1048576)    hfinal : fp32 [256][1024]
//   [148897792, +16384)      flags  : int flag[bt][jt] at ((bt*32+jt)*16)*4B
//                            (one 64B line per producer; value = steps done)

__global__ __launch_bounds__(256) void prep_w(const float* __restrict__ Wih,
                                              const float* __restrict__ Whh,
                                              uint16_t* __restrict__ wp,
                                              int* __restrict__ flags) {
  if (blockIdx.x < 16) {
    __hip_atomic_store(&flags[blockIdx.x * 256 + threadIdx.x], 0,
                       __ATOMIC_RELAXED, __HIP_MEMORY_SCOPE_AGENT);
  }
  int idx = blockIdx.x * 256 + threadIdx.x;     // 786432 total
  int l = idx & 63;
  int r = idx >> 6;
  int s = r % 48; r /= 48;
  int q = r & 1;  r >>= 1;
  int w = r & 3;  r >>= 2;
  int jt = r;                                    // 0..31
  int row = w * 1024 + jt * 32 + q * 16 + (l & 15);
  int kb  = s * 32 + (l >> 4) * 8;               // 0..1528
  const float* src = (kb < 1024) ? (Whh + (size_t)row * 1024 + kb)
                                 : (Wih + (size_t)row * 512 + (kb - 1024));
  uint32_t d0 = (uint32_t)f2bf(src[0]) | ((uint32_t)f2bf(src[1]) << 16);
  uint32_t d1 = (uint32_t)f2bf(src[2]) | ((uint32_t)f2bf(src[3]) << 16);
  uint32_t d2 = (uint32_t)f2bf(src[4]) | ((uint32_t)f2bf(src[5]) << 16);
  uint32_t d3 = (uint32_t)f2bf(src[6]) | ((uint32_t)f2bf(src[7]) << 16);
  *(uint4*)(wp + (size_t)idx * 8) = make_uint4(d0, d1, d2, d3);
}

__global__ __launch_bounds__(256) void prep_x(const float* __restrict__ x,
                                              uint16_t* __restrict__ xp) {
  int idx = blockIdx.x * 256 + threadIdx.x;     // 8388608 total
  int l = idx & 63;
  int r = idx >> 6;
  int mt = r & 1;  r >>= 1;
  int ks = r & 15; r >>= 4;
  int bt = r & 7;  r >>= 3;
  int t  = r;                                    // 0..511
  int b = bt * 32 + mt * 16 + (l & 15);
  int k = ks * 32 + (l >> 4) * 8;
  const float* src = x + ((size_t)b * 512 + t) * 512 + k;
  uint32_t d0 = (uint32_t)f2bf(src[0]) | ((uint32_t)f2bf(src[1]) << 16);
  uint32_t d1 = (uint32_t)f2bf(src[2]) | ((uint32_t)f2bf(src[3]) << 16);
  uint32_t d2 = (uint32_t)f2bf(src[4]) | ((uint32_t)f2bf(src[5]) << 16);
  uint32_t d3 = (uint32_t)f2bf(src[6]) | ((uint32_t)f2bf(src[7]) << 16);
  *(uint4*)(xp + (size_t)idx * 8) = make_uint4(d0, d1, d2, d3);
}

// LDS: hbuf 65536 | xbuf0 32768 | xbuf1 32768 | zl [4][32][36] f32 (18432)
// total 149504 dynamic. FC phase reuses bytes [0,131584) as hl[32][1028] f32.
__global__ __launch_bounds__(512, 2) void lstm_main(
    const uint16_t* __restrict__ wpack,
    const uint16_t* __restrict__ xpack,
    uint16_t* __restrict__ hpack,
    float* __restrict__ hfinal,
    int* flags,
    const float* __restrict__ bih,
    const float* __restrict__ bhh,
    const float* __restrict__ Wfc,
    const float* __restrict__ bfc,
    float* __restrict__ out) {
  extern __shared__ char smem[];

  const int tid = threadIdx.x;
  const int w8  = tid >> 6;         // wave 0..7
  const int g8  = w8 & 3;           // gate index (i,f,g,o)
  const int p8  = w8 >> 2;          // k-half 0/1 (wave-uniform)
  const int l   = tid & 63;
  const int jt  = blockIdx.x >> 3;  // unit tile 0..31
  const int bt  = blockIdx.x & 7;   // batch tile 0..7

  char* const hbuf  = smem;
  char* const xbuf0 = smem + 65536;
  char* const xbuf1 = smem + 98304;
  float* const zl   = (float*)(smem + 131072);  // [4][32][36]

  // per-producer flag line this block owns, and the flag line lane l polls
  int* const flag_self = flags + ((bt * 32 + jt) << 4);
  const int* const flag_poll = flags + ((bt * 32 + (l & 31)) << 4);
  int spin_budget = 150000;  // ~50ms worst case; stall -> fast fail, not hang

  // ---- resident B fragments (this wave's k-half): fb[q][j]
  //      j<16  -> W_hh k-slice s = p8*16 + j
  //      j>=16 -> W_ih k-slice s = 32 + p8*8 + (j-16)
  bf16x8 fb[2][24];
#pragma unroll
  for (int q = 0; q < 2; ++q) {
#pragma unroll
    for (int j = 0; j < 24; ++j) {
      int s = (j < 16) ? (p8 * 16 + j) : (32 + p8 * 8 + (j - 16));
      union { uint4 u; bf16x8 b; } cv;
      cv.u = *(const uint4*)(wpack +
              (size_t)(((jt * 4 + g8) * 2 + q) * 48 + s) * 512 + (size_t)l * 8);
      fb[q][j] = cv.b;
    }
  }

  // cell-update mapping: 512 threads own 2 cells each
  const int umt = tid >> 8;                  // 0/1 (batch half)
  const int ul  = (tid >> 2) & 63;           // frag lane
  const int uj  = (tid & 3) * 2;             // unit pair within 8-block
  const int um  = umt * 16 + (ul & 15);      // batch row in tile
  const int uu0 = (ul >> 4) * 8 + uj;        // unit in tile (2 consecutive)
  float c0 = 0.f, c1 = 0.f;

  // per-thread biases for the I-phase activation: bg[gate][cell 0/1]
  float bg[4][2];
#pragma unroll
  for (int g = 0; g < 4; ++g) {
    int u0 = g * 1024 + jt * 32 + uu0;
    bg[g][0] = bih[u0]     + bhh[u0];
    bg[g][1] = bih[u0 + 1] + bhh[u0 + 1];
  }

  // zero zl (each thread zeroes exactly the 8 slots it will read in I)
#pragma unroll
  for (int g = 0; g < 4; ++g)
    *(f32x2*)&zl[(g * 32 + um) * 36 + uu0] = (f32x2){0.f, 0.f};

  // prestage x(t=0): 32 chunks over 8 waves
  {
    const uint16_t* src = xpack + (size_t)bt * 16384;
#pragma unroll
    for (int i = 0; i < 4; ++i) {
      int ci = w8 * 4 + i;
      __builtin_amdgcn_global_load_lds(
          (const __attribute__((address_space(1))) void*)(src + (size_t)ci * 512 + (size_t)l * 8),
          (__attribute__((address_space(3))) void*)(xbuf0 + ci * 1024), 16, 0, 0);
    }
  }
  __syncthreads();

  for (int t = 0; t < T_STEPS; ++t) {
    f32x4 acc[2][2];
#pragma unroll
    for (int mt = 0; mt < 2; ++mt)
#pragma unroll
      for (int q = 0; q < 2; ++q) acc[mt][q] = (f32x4){0.f, 0.f, 0.f, 0.f};

    const char* xc = (t & 1) ? xbuf1 : xbuf0;

    // B: this wave's x slices, first half (covers poll jitter; LDS-only)
#pragma unroll
    for (int jj = 0; jj < 4; ++jj) {
      int ks = p8 * 8 + jj;
#pragma unroll
      for (int mt = 0; mt < 2; ++mt) {
        bf16x8 a = *(const bf16x8*)(xc + ((ks * 2 + mt) * 64 + l) * 16);
        acc[mt][0] = __builtin_amdgcn_mfma_f32_16x16x32_bf16(a, fb[0][16 + jj], acc[mt][0], 0, 0, 0);
        acc[mt][1] = __builtin_amdgcn_mfma_f32_16x16x32_bf16(a, fb[1][16 + jj], acc[mt][1], 0, 0, 0);
      }
    }

    // C: flag barrier for h(t-1) — wave 0 polls 32 flags with one 32-lane
    // vector load, everyone else parks at the barrier.
    if (t > 0) {
      if (tid < 64) {
        for (;;) {
          int v = __hip_atomic_load(flag_poll, __ATOMIC_RELAXED,
                                    __HIP_MEMORY_SCOPE_AGENT);
          if (__all(v >= t)) break;
          if (--spin_budget < 0) break;
          __builtin_amdgcn_s_sleep(1);
        }
      }
      __syncthreads();
    }

    // A: x(t+1) prefetch (4 chunks/wave)
    if (t + 1 < T_STEPS) {
      const uint16_t* src = xpack + (size_t)((t + 1) * 8 + bt) * 16384;
      char* dst = ((t + 1) & 1) ? xbuf1 : xbuf0;
#pragma unroll
      for (int i = 0; i < 4; ++i) {
        int ci = w8 * 4 + i;
        __builtin_amdgcn_global_load_lds(
            (const __attribute__((address_space(1))) void*)(src + (size_t)ci * 512 + (size_t)l * 8),
            (__attribute__((address_space(3))) void*)(dst + ci * 1024), 16, 0, 0);
      }
    }

    // C2: h(t-1) loads, aux=17 (SC0|SC1: read at LLC, the coherence point),
    // 8 chunks/wave (64 total = full 64KB h tile)
    if (t > 0) {
      const uint16_t* hs = hpack + (size_t)(((t - 1) & 1) * 8 + bt) * 32768;
#pragma unroll
      for (int i = 0; i < 8; ++i) {
        int ci = w8 * 8 + i;
        __builtin_amdgcn_global_load_lds(
            (const __attribute__((address_space(1))) void*)(hs + (size_t)ci * 512 + (size_t)l * 8),
            (__attribute__((address_space(3))) void*)(hbuf + ci * 1024), 16, 0, 17);
      }
    }

    // D: this wave's x slices, second half (covers h-load flight)
#pragma unroll
    for (int jj = 4; jj < 8; ++jj) {
      int ks = p8 * 8 + jj;
#pragma unroll
      for (int mt = 0; mt < 2; ++mt) {
        bf16x8 a = *(const bf16x8*)(xc + ((ks * 2 + mt) * 64 + l) * 16);
        acc[mt][0] = __builtin_amdgcn_mfma_f32_16x16x32_bf16(a, fb[0][16 + jj], acc[mt][0], 0, 0, 0);
        acc[mt][1] = __builtin_amdgcn_mfma_f32_16x16x32_bf16(a, fb[1][16 + jj], acc[mt][1], 0, 0, 0);
      }
    }

    // E: drain loads (h + next-x), then this wave's h-part (16 slices)
    __syncthreads();
    if (t > 0) {
#pragma unroll
      for (int j = 0; j < 16; ++j) {
        int s = p8 * 16 + j;
#pragma unroll
        for (int mt = 0; mt < 2; ++mt) {
          bf16x8 a = *(const bf16x8*)(hbuf + ((s * 2 + mt) * 64 + l) * 16);
          acc[mt][0] = __builtin_amdgcn_mfma_f32_16x16x32_bf16(a, fb[0][j], acc[mt][0], 0, 0, 0);
          acc[mt][1] = __builtin_amdgcn_mfma_f32_16x16x32_bf16(a, fb[1][j], acc[mt][1], 0, 0, 0);
        }
      }
    }

    // G: barrier-free k-reduction — both k-half waves ds_add_f32 raw
    // partials into zl (zeroed by I of the previous step; ordered by J/C/E
    // barriers). All indices compile-time after unroll (rule #20).
#pragma unroll
    for (int mt = 0; mt < 2; ++mt) {
#pragma unroll
      for (int q = 0; q < 2; ++q) {
        f32x4 v = acc[mt][q];
#pragma unroll
        for (int r = 0; r < 4; ++r) {
          int m  = mt * 16 + (l >> 4) * 4 + r;   // C layout: row=(lane>>4)*4+reg
          int uu = q * 16 + (l & 15);            //           col=lane&15
          (void)__hip_atomic_fetch_add(&zl[(g8 * 32 + m) * 36 + uu], v[r],
                                       __ATOMIC_RELAXED,
                                       __HIP_MEMORY_SCOPE_WORKGROUP);
        }
      }
    }
    __syncthreads();  // H: all partials summed

    // I: read raw gate sums, add bias, activate (i,f,o sigmoid; g tanh),
    // cell update (c in regs), pack h, LLC agent stores, re-zero zl slots.
    {
      const f32x2 si = *(const f32x2*)&zl[(0 * 32 + um) * 36 + uu0];
      const f32x2 sf = *(const f32x2*)&zl[(1 * 32 + um) * 36 + uu0];
      const f32x2 sg = *(const f32x2*)&zl[(2 * 32 + um) * 36 + uu0];
      const f32x2 so = *(const f32x2*)&zl[(3 * 32 + um) * 36 + uu0];
#pragma unroll
      for (int g = 0; g < 4; ++g)
        *(f32x2*)&zl[(g * 32 + um) * 36 + uu0] = (f32x2){0.f, 0.f};
      float gi0 = sigmoid_f(si[0] + bg[0][0]), gi1 = sigmoid_f(si[1] + bg[0][1]);
      float gf0 = sigmoid_f(sf[0] + bg[1][0]), gf1 = sigmoid_f(sf[1] + bg[1][1]);
      float gg0 = tanh_f   (sg[0] + bg[2][0]), gg1 = tanh_f   (sg[1] + bg[2][1]);
      float go0 = sigmoid_f(so[0] + bg[3][0]), go1 = sigmoid_f(so[1] + bg[3][1]);
      c0 = gf0 * c0 + gi0 * gg0;
      c1 = gf1 * c1 + gi1 * gg1;
      float h0 = go0 * tanh_f(c0);
      float h1 = go1 * tanh_f(c1);
      uint32_t pv = (uint32_t)f2bf(h0) | ((uint32_t)f2bf(h1) << 16);
      uint16_t* hp = hpack +
          (size_t)((((t & 1) * 8 + bt) * 32 + jt) * 2 + umt) * 512 + (size_t)ul * 8 + uj;
      __hip_atomic_store((uint32_t*)hp, pv,
                         __ATOMIC_RELAXED, __HIP_MEMORY_SCOPE_AGENT);
      if (t == T_STEPS - 1) {
        unsigned long long q0 = ((unsigned long long)__float_as_uint(h1) << 32) |
                                (unsigned long long)__float_as_uint(h0);
        unsigned long long* fp = (unsigned long long*)
            &hfinal[(size_t)(bt * 32 + um) * 1024 + jt * 32 + uu0];
        __hip_atomic_store(fp, q0, __ATOMIC_RELAXED, __HIP_MEMORY_SCOPE_AGENT);
      }
    }

    // J: all stores at LLC (vmcnt(0) per wave, joined by the barrier), then
    // announce: flag = t+1 via a plain agent store on this block's own line.
    asm volatile("s_waitcnt vmcnt(0)" ::: "memory");
    __syncthreads();
    if (tid == 0) {
      __hip_atomic_store(flag_self, t + 1, __ATOMIC_RELAXED,
                         __HIP_MEMORY_SCOPE_AGENT);
    }
  }

  // ---- final FC: out = hT @ Wfc^T + bfc (fp32) ----
  if (tid < 64) {
    for (;;) {
      int v = __hip_atomic_load(flag_poll, __ATOMIC_RELAXED,
                                __HIP_MEMORY_SCOPE_AGENT);
      if (__all(v >= T_STEPS)) break;
      if (--spin_budget < 0) break;
      __builtin_amdgcn_s_sleep(1);
    }
  }
  __syncthreads();

  float* const hl = (float*)smem;   // [32][1028] padded
  {
    const unsigned long long* hq =
        (const unsigned long long*)(hfinal + (size_t)bt * 32 * 1024);
#pragma unroll 4
    for (int i = 0; i < 32; ++i) {
      int d   = i * 512 + tid;      // 0..16383
      int row = d >> 9;
      int c2  = d & 511;
      unsigned long long v = __hip_atomic_load(hq + (size_t)row * 512 + c2,
                                               __ATOMIC_RELAXED, __HIP_MEMORY_SCOPE_AGENT);
      *(unsigned long long*)&hl[row * 1028 + c2 * 2] = v;
    }
  }
  __syncthreads();
  {
    const int bl = tid >> 4;          // batch row 0..31
    const int oo = tid & 15;          // output within jt tile
    const int o0 = jt * 16 + oo;
    float a0 = 0.f;
    const float* hrow = &hl[bl * 1028];
    const float* w0p  = Wfc + (size_t)o0 * 1024;
#pragma unroll 8
    for (int k = 0; k < 1024; k += 4) {
      f32x4 hv = *(const f32x4*)&hrow[k];
      f32x4 w0 = *(const f32x4*)&w0p[k];
      a0 += hv[0] * w0[0] + hv[1] * w0[1] + hv[2] * w0[2] + hv[3] * w0[3];
    }
    int b = bt * 32 + bl;
    out[(size_t)b * 512 + o0] = a0 + bfc[o0];
  }
}

extern "C" void kernel_launch(void* const* d_in, const int* in_sizes, int n_in,
                              void* d_out, int out_size, void* d_ws, size_t ws_size,
                              hipStream_t stream) {
  const float* x   = (const float*)d_in[0];
  const float* Wih = (const float*)d_in[1];
  const float* Whh = (const float*)d_in[2];
  const float* bih = (const float*)d_in[3];
  const float* bhh = (const float*)d_in[4];
  const float* Wfc = (const float*)d_in[5];
  const float* bfc = (const float*)d_in[6];
  float* out = (float*)d_out;

  char* ws = (char*)d_ws;
  uint16_t* wp  = (uint16_t*)(ws);
  uint16_t* xp  = (uint16_t*)(ws + 12582912);
  uint16_t* hp  = (uint16_t*)(ws + 146800640);
  float*    hf  = (float*)   (ws + 147849216);
  int*      fl  = (int*)     (ws + 148897792);

  (void)hipFuncSetAttribute((const void*)lstm_main,
                            hipFuncAttributeMaxDynamicSharedMemorySize, 149504);

  hipLaunchKernelGGL(prep_w, dim3(3072), dim3(256), 0, stream, Wih, Whh, wp, fl);
  hipLaunchKernelGGL(prep_x, dim3(32768), dim3(256), 0, stream, x, xp);
  hipLaunchKernelGGL(lstm_main, dim3(256), dim3(512), 149504, stream,
                     wp, xp, hp, hf, fl, bih, bhh, Wfc, bfc, out);
}

// Round 8
// 4030.246 us; speedup vs baseline: 2.3064x; 2.3064x over previous
//
#include <hip/hip_runtime.h>
#include <stdint.h>

// LSTM (B=256,T=512,I=512,H=1024) + FC on MI355X.
// Persistent 256-block kernel, 1 block/CU, 4 waves (256 thr). Block owns
// (jt: 32 hidden units -> 128 gate rows, bt: 32 batch rows). Weights fully
// resident as MFMA B-frags (fb[2][48], 384 regs/wave). h exchanged via LLC
// with r2-proven idioms ONLY: agent relaxed atomic stores (land at LLC),
// global_load_lds aux=17 (read at LLC), agent relaxed loads, per-producer
// flags on private 64B lines.
// ROUND 14: TWO-CHAIN HALF-STEP PIPELINE. Rounds 5-7 (8-wave K-split) never
// beat the 4-wave baseline: occupancy gains were eaten by exchange
// serialization (r6 +830us) and LDS atomics are poison (r7: 2x, MfmaUtil 7%).
// Reverted to the 4-wave structure. New idea: the block's 32 batch rows are
// TWO INDEPENDENT recurrence chains (mt=0 rows 0-15, mt=1 rows 16-31) — the
// LSTM couples blocks only within a chain. Each step becomes two half-steps,
// chains offset by half a step:
//   HS(X,t): M: x+h MFMAs chain X (96/wave, acc only 8 regs)
//            poll+issue h_Y loads (Y's exchange flight starts)
//            G: activations X -> zl | H1 | I: cell update X, store h_X
//            vmcnt(0) (drains h_X stores AND h_Y loads, covered by G+I VALU)
//            H2 | flag_X = t+1
// The previously-serial per-step chain {drain->flag->remote poll->load
// flight} now hides under the OTHER chain's compute. Exchange bytes, MFMA
// count, flag protocol, ping-pong phase safety: all unchanged from baseline.
// Flags: chain A at +0, chain B at +8 ints on the same private 64B line.
// All waves poll independently (no poll barrier). c in fp32 regs. FC fp32.

#define T_STEPS 512

typedef __bf16 bf16x8 __attribute__((ext_vector_type(8)));
typedef float  f32x4  __attribute__((ext_vector_type(4)));
typedef float  f32x2  __attribute__((ext_vector_type(2)));

__device__ __forceinline__ uint16_t f2bf(float f) {
  uint32_t u = __float_as_uint(f);
  u += 0x7fffu + ((u >> 16) & 1u);   // RNE
  return (uint16_t)(u >> 16);
}
__device__ __forceinline__ float sigmoid_f(float z) {
  return 1.0f / (1.0f + __expf(-z));
}
__device__ __forceinline__ float tanh_f(float x) {
  float ax = __builtin_fabsf(x);
  float e  = __expf(-2.0f * ax);
  float r  = (1.0f - e) / (1.0f + e);
  return __builtin_copysignf(r, x);
}

// ws layout (bytes):
//   [0, 12582912)            Wpack  : bf16 frags [jt32][w4][q2][s48][lane64][8]
//   [12582912, +134217728)   xpack  : bf16 frags [t512][bt8][ks16][mt2][lane64][8]
//   [146800640, +1048576)    hpack  : bf16 frags [phase2][bt8][jt32][mt2][lane64][8]
//   [147849216, +1048576)    hfinal : fp32 [256][1024]
//   [148897792, +16384)      flags  : int at ((bt*32+jt)*16 + chain*8)*4B
//                            (one 64B line per producer; value = steps done)

__global__ __launch_bounds__(256) void prep_w(const float* __restrict__ Wih,
                                              const float* __restrict__ Whh,
                                              uint16_t* __restrict__ wp,
                                              int* __restrict__ flags) {
  if (blockIdx.x < 16) {
    __hip_atomic_store(&flags[blockIdx.x * 256 + threadIdx.x], 0,
                       __ATOMIC_RELAXED, __HIP_MEMORY_SCOPE_AGENT);
  }
  int idx = blockIdx.x * 256 + threadIdx.x;     // 786432 total
  int l = idx & 63;
  int r = idx >> 6;
  int s = r % 48; r /= 48;
  int q = r & 1;  r >>= 1;
  int w = r & 3;  r >>= 2;
  int jt = r;                                    // 0..31
  int row = w * 1024 + jt * 32 + q * 16 + (l & 15);
  int kb  = s * 32 + (l >> 4) * 8;               // 0..1528
  const float* src = (kb < 1024) ? (Whh + (size_t)row * 1024 + kb)
                                 : (Wih + (size_t)row * 512 + (kb - 1024));
  uint32_t d0 = (uint32_t)f2bf(src[0]) | ((uint32_t)f2bf(src[1]) << 16);
  uint32_t d1 = (uint32_t)f2bf(src[2]) | ((uint32_t)f2bf(src[3]) << 16);
  uint32_t d2 = (uint32_t)f2bf(src[4]) | ((uint32_t)f2bf(src[5]) << 16);
  uint32_t d3 = (uint32_t)f2bf(src[6]) | ((uint32_t)f2bf(src[7]) << 16);
  *(uint4*)(wp + (size_t)idx * 8) = make_uint4(d0, d1, d2, d3);
}

__global__ __launch_bounds__(256) void prep_x(const float* __restrict__ x,
                                              uint16_t* __restrict__ xp) {
  int idx = blockIdx.x * 256 + threadIdx.x;     // 8388608 total
  int l = idx & 63;
  int r = idx >> 6;
  int mt = r & 1;  r >>= 1;
  int ks = r & 15; r >>= 4;
  int bt = r & 7;  r >>= 3;
  int t  = r;                                    // 0..511
  int b = bt * 32 + mt * 16 + (l & 15);
  int k = ks * 32 + (l >> 4) * 8;
  const float* src = x + ((size_t)b * 512 + t) * 512 + k;
  uint32_t d0 = (uint32_t)f2bf(src[0]) | ((uint32_t)f2bf(src[1]) << 16);
  uint32_t d1 = (uint32_t)f2bf(src[2]) | ((uint32_t)f2bf(src[3]) << 16);
  uint32_t d2 = (uint32_t)f2bf(src[4]) | ((uint32_t)f2bf(src[5]) << 16);
  uint32_t d3 = (uint32_t)f2bf(src[6]) | ((uint32_t)f2bf(src[7]) << 16);
  *(uint4*)(xp + (size_t)idx * 8) = make_uint4(d0, d1, d2, d3);
}

// One half-step for chain X (literal 0/1). DO_LOAD: fetch h of chain 1-X,
// step S_LOAD, into its hbuf (poll flag first). DO_PREF: prefetch x(t+1).
// C0/C1: this chain's cell registers (names, so indices stay literal).
#define HALF_STEP(X, DO_LOAD, S_LOAD, DO_PREF, C0, C1)                        \
  do {                                                                        \
    f32x4 acc0 = (f32x4){0.f, 0.f, 0.f, 0.f};                                 \
    f32x4 acc1 = (f32x4){0.f, 0.f, 0.f, 0.f};                                 \
    const char* xc = (t & 1) ? xbuf1 : xbuf0;                                 \
    /* M: x-part (16 slices, mt = X) */                                       \
    _Pragma("unroll")                                                         \
    for (int s = 0; s < 16; ++s) {                                            \
      bf16x8 a = *(const bf16x8*)(xc + ((s * 2 + (X)) * 64 + l) * 16);        \
      acc0 = __builtin_amdgcn_mfma_f32_16x16x32_bf16(a, fb[0][32 + s], acc0, 0, 0, 0); \
      acc1 = __builtin_amdgcn_mfma_f32_16x16x32_bf16(a, fb[1][32 + s], acc1, 0, 0, 0); \
    }                                                                         \
    /* M: h-part (32 slices from this chain's hbuf) */                        \
    if (t > 0) {                                                              \
      const char* hb = (X) ? hbufB : hbufA;                                   \
      _Pragma("unroll")                                                       \
      for (int s = 0; s < 32; ++s) {                                          \
        bf16x8 a = *(const bf16x8*)(hb + (s * 64 + l) * 16);                  \
        acc0 = __builtin_amdgcn_mfma_f32_16x16x32_bf16(a, fb[0][s], acc0, 0, 0, 0); \
        acc1 = __builtin_amdgcn_mfma_f32_16x16x32_bf16(a, fb[1][s], acc1, 0, 0, 0); \
      }                                                                       \
    }                                                                         \
    /* poll (every wave independently) + issue other chain's h loads */       \
    if (DO_LOAD) {                                                            \
      const int tgt = (S_LOAD) + 1;                                           \
      const int* fp = (X) ? flag_pollA : flag_pollB;                          \
      for (;;) {                                                              \
        int v = __hip_atomic_load(fp, __ATOMIC_RELAXED,                       \
                                  __HIP_MEMORY_SCOPE_AGENT);                  \
        if (__all(v >= tgt)) break;                                           \
        if (--spin_budget < 0) break;                                         \
        __builtin_amdgcn_s_sleep(1);                                          \
      }                                                                       \
      const uint16_t* hs = hpack +                                            \
          (size_t)(((S_LOAD) & 1) * 8 + bt) * 32768 + (1 - (X)) * 512;        \
      char* hd = (X) ? hbufA : hbufB;                                         \
      _Pragma("unroll")                                                       \
      for (int i = 0; i < 8; ++i) {                                           \
        int ci = w * 8 + i;                                                   \
        __builtin_amdgcn_global_load_lds(                                     \
            (const __attribute__((address_space(1))) void*)(hs + (size_t)ci * 1024 + (size_t)l * 8), \
            (__attribute__((address_space(3))) void*)(hd + ci * 1024), 16, 0, 17); \
      }                                                                       \
    }                                                                         \
    /* x(t+1) prefetch (A-half only) — flight hides under G+I */              \
    if ((DO_PREF) && t + 1 < T_STEPS) {                                       \
      const uint16_t* src = xpack + (size_t)((t + 1) * 8 + bt) * 16384;       \
      char* dst = ((t + 1) & 1) ? xbuf1 : xbuf0;                              \
      _Pragma("unroll")                                                       \
      for (int i = 0; i < 8; ++i) {                                           \
        int ci = w * 8 + i;                                                   \
        __builtin_amdgcn_global_load_lds(                                     \
            (const __attribute__((address_space(1))) void*)(src + (size_t)ci * 512 + (size_t)l * 8), \
            (__attribute__((address_space(3))) void*)(dst + ci * 1024), 16, 0, 0); \
      }                                                                       \
    }                                                                         \
    /* G: activations (wave = gate), rows X*16..X*16+15 of zl */              \
    {                                                                         \
      f32x4 v = acc0; float bq = bias0;                                       \
      _Pragma("unroll")                                                       \
      for (int r = 0; r < 4; ++r) {                                           \
        float z = v[r] + bq;                                                  \
        float a = (w == 2) ? tanh_f(z) : sigmoid_f(z);                        \
        int m  = (X) * 16 + (l >> 4) * 4 + r;                                 \
        zl[(w * 32 + m) * 36 + (l & 15)] = a;                                 \
      }                                                                       \
    }                                                                         \
    {                                                                         \
      f32x4 v = acc1; float bq = bias1;                                       \
      _Pragma("unroll")                                                       \
      for (int r = 0; r < 4; ++r) {                                           \
        float z = v[r] + bq;                                                  \
        float a = (w == 2) ? tanh_f(z) : sigmoid_f(z);                        \
        int m  = (X) * 16 + (l >> 4) * 4 + r;                                 \
        zl[(w * 32 + m) * 36 + 16 + (l & 15)] = a;                            \
      }                                                                       \
    }                                                                         \
    __syncthreads(); /* H1: zl ready */                                       \
    /* I: cell update, 2 cells/thread (rows X*16+ir, units u0,u0+1) */        \
    {                                                                         \
      const int ir = tid >> 4;                                                \
      const int u0 = (tid & 15) * 2;                                          \
      const f32x2 gi = *(const f32x2*)&zl[(0 * 32 + (X) * 16 + ir) * 36 + u0];\
      const f32x2 gf = *(const f32x2*)&zl[(1 * 32 + (X) * 16 + ir) * 36 + u0];\
      const f32x2 gg = *(const f32x2*)&zl[(2 * 32 + (X) * 16 + ir) * 36 + u0];\
      const f32x2 go = *(const f32x2*)&zl[(3 * 32 + (X) * 16 + ir) * 36 + u0];\
      C0 = gf[0] * C0 + gi[0] * gg[0];                                        \
      C1 = gf[1] * C1 + gi[1] * gg[1];                                        \
      float h0 = go[0] * tanh_f(C0);                                          \
      float h1 = go[1] * tanh_f(C1);                                          \
      uint32_t pv = (uint32_t)f2bf(h0) | ((uint32_t)f2bf(h1) << 16);          \
      int hl_lane = ir + ((u0 >> 3) << 4);                                    \
      uint16_t* hp = hpack +                                                  \
          (size_t)((((t & 1) * 8 + bt) * 32 + jt) * 2 + (X)) * 512 +          \
          hl_lane * 8 + (u0 & 7);                                             \
      __hip_atomic_store((uint32_t*)hp, pv,                                   \
                         __ATOMIC_RELAXED, __HIP_MEMORY_SCOPE_AGENT);         \
      if (t == T_STEPS - 1) {                                                 \
        unsigned long long q0 = ((unsigned long long)__float_as_uint(h1) << 32) | \
                                (unsigned long long)__float_as_uint(h0);      \
        unsigned long long* fpf = (unsigned long long*)                       \
            &hfinal[(size_t)(bt * 32 + (X) * 16 + ir) * 1024 + jt * 32 + u0]; \
        __hip_atomic_store(fpf, q0, __ATOMIC_RELAXED, __HIP_MEMORY_SCOPE_AGENT); \
      }                                                                       \
    }                                                                         \
    /* drain h_X stores + h_Y loads (+x pref), then announce */               \
    asm volatile("s_waitcnt vmcnt(0)" ::: "memory");                          \
    __syncthreads(); /* H2 */                                                 \
    if (tid == 0) {                                                           \
      __hip_atomic_store(flag_self + (X) * 8, t + 1,                          \
                         __ATOMIC_RELAXED, __HIP_MEMORY_SCOPE_AGENT);         \
    }                                                                         \
  } while (0)

// LDS: hbufA 32768 | hbufB 32768 | xbuf0 32768 | xbuf1 32768 | zl 18432
// total 149504 dynamic. FC phase reuses bytes [0,131584) as hl[32][1028] f32.
__global__ __launch_bounds__(256, 1) void lstm_main(
    const uint16_t* __restrict__ wpack,
    const uint16_t* __restrict__ xpack,
    uint16_t* __restrict__ hpack,
    float* __restrict__ hfinal,
    int* flags,
    const float* __restrict__ bih,
    const float* __restrict__ bhh,
    const float* __restrict__ Wfc,
    const float* __restrict__ bfc,
    float* __restrict__ out) {
  extern __shared__ char smem[];

  const int tid = threadIdx.x;
  const int w   = tid >> 6;         // wave = gate index (i,f,g,o)
  const int l   = tid & 63;
  const int jt  = blockIdx.x >> 3;  // unit tile 0..31
  const int bt  = blockIdx.x & 7;   // batch tile 0..7

  char* const hbufA = smem;
  char* const hbufB = smem + 32768;
  char* const xbuf0 = smem + 65536;
  char* const xbuf1 = smem + 98304;
  float* const zl   = (float*)(smem + 131072);  // [4][32][36]

  // flag lines: this block's (chain A at +0 ints, B at +8), and poll targets
  int* const flag_self = flags + ((bt * 32 + jt) << 4);
  const int* const flag_pollA = flags + ((bt * 32 + (l & 31)) << 4);
  const int* const flag_pollB = flag_pollA + 8;
  int spin_budget = 150000;  // ~50ms worst case; stall -> fast fail, not hang

  // ---- resident B fragments: fb[q][s], s<32 -> W_hh k, s>=32 -> W_ih k ----
  bf16x8 fb[2][48];
#pragma unroll
  for (int q = 0; q < 2; ++q) {
#pragma unroll
    for (int s = 0; s < 48; ++s) {
      union { uint4 u; bf16x8 b; } cv;
      cv.u = *(const uint4*)(wpack +
              (size_t)(((jt * 4 + w) * 2 + q) * 48 + s) * 512 + (size_t)l * 8);
      fb[q][s] = cv.b;
    }
  }

  float bias0, bias1;
  {
    int u0b = jt * 32 + (l & 15);
    bias0 = bih[w * 1024 + u0b]      + bhh[w * 1024 + u0b];
    bias1 = bih[w * 1024 + u0b + 16] + bhh[w * 1024 + u0b + 16];
  }

  float cA0 = 0.f, cA1 = 0.f, cB0 = 0.f, cB1 = 0.f;

  // prestage x(t=0)
  {
    const uint16_t* src = xpack + (size_t)bt * 16384;
#pragma unroll
    for (int i = 0; i < 8; ++i) {
      int ci = w * 8 + i;
      __builtin_amdgcn_global_load_lds(
          (const __attribute__((address_space(1))) void*)(src + (size_t)ci * 512 + (size_t)l * 8),
          (__attribute__((address_space(3))) void*)(xbuf0 + ci * 1024), 16, 0, 0);
    }
  }
  __syncthreads();

  for (int t = 0; t < T_STEPS; ++t) {
    // half-step A: compute chain A step t; fetch h_B(t-1) for the B half
    HALF_STEP(0, (t > 0), (t - 1), 1, cA0, cA1);
    // half-step B: compute chain B step t; fetch h_A(t) for next A half
    HALF_STEP(1, (t < T_STEPS - 1), (t), 0, cB0, cB1);
  }

  // ---- final FC: out = hT @ Wfc^T + bfc (fp32) ----
  // poll both chains (lanes 0-31: A, 32-63: B) >= T_STEPS
  if (tid < 64) {
    const int* fp = (l < 32) ? flag_pollA : flag_pollB;
    for (;;) {
      int v = __hip_atomic_load(fp, __ATOMIC_RELAXED, __HIP_MEMORY_SCOPE_AGENT);
      if (__all(v >= T_STEPS)) break;
      if (--spin_budget < 0) break;
      __builtin_amdgcn_s_sleep(1);
    }
  }
  __syncthreads();

  float* const hl = (float*)smem;   // [32][1028] padded
  {
    const unsigned long long* hq =
        (const unsigned long long*)(hfinal + (size_t)bt * 32 * 1024);
#pragma unroll 4
    for (int i = 0; i < 64; ++i) {
      int d   = i * 256 + tid;      // 0..16383
      int row = d >> 9;
      int c2  = d & 511;
      unsigned long long v = __hip_atomic_load(hq + (size_t)row * 512 + c2,
                                               __ATOMIC_RELAXED, __HIP_MEMORY_SCOPE_AGENT);
      *(unsigned long long*)&hl[row * 1028 + c2 * 2] = v;
    }
  }
  __syncthreads();
  {
    const int bl = tid >> 3;
    const int oo = tid & 7;
    const int o0 = jt * 16 + oo * 2;
    float a0 = 0.f, a1 = 0.f;
    const float* hrow = &hl[bl * 1028];
    const float* w0p  = Wfc + (size_t)o0 * 1024;
    const float* w1p  = w0p + 1024;
#pragma unroll 8
    for (int k = 0; k < 1024; k += 4) {
      f32x4 hv = *(const f32x4*)&hrow[k];
      f32x4 w0 = *(const f32x4*)&w0p[k];
      f32x4 w1 = *(const f32x4*)&w1p[k];
      a0 += hv[0] * w0[0] + hv[1] * w0[1] + hv[2] * w0[2] + hv[3] * w0[3];
      a1 += hv[0] * w1[0] + hv[1] * w1[1] + hv[2] * w1[2] + hv[3] * w1[3];
    }
    int b = bt * 32 + bl;
    out[(size_t)b * 512 + o0]     = a0 + bfc[o0];
    out[(size_t)b * 512 + o0 + 1] = a1 + bfc[o0 + 1];
  }
}

extern "C" void kernel_launch(void* const* d_in, const int* in_sizes, int n_in,
                              void* d_out, int out_size, void* d_ws, size_t ws_size,
                              hipStream_t stream) {
  const float* x   = (const float*)d_in[0];
  const float* Wih = (const float*)d_in[1];
  const float* Whh = (const float*)d_in[2];
  const float* bih = (const float*)d_in[3];
  const float* bhh = (const float*)d_in[4];
  const float* Wfc = (const float*)d_in[5];
  const float* bfc = (const float*)d_in[6];
  float* out = (float*)d_out;

  char* ws = (char*)d_ws;
  uint16_t* wp  = (uint16_t*)(ws);
  uint16_t* xp  = (uint16_t*)(ws + 12582912);
  uint16_t* hp  = (uint16_t*)(ws + 146800640);
  float*    hf  = (float*)   (ws + 147849216);
  int*      fl  = (int*)     (ws + 148897792);

  (void)hipFuncSetAttribute((const void*)lstm_main,
                            hipFuncAttributeMaxDynamicSharedMemorySize, 149504);

  hipLaunchKernelGGL(prep_w, dim3(3072), dim3(256), 0, stream, Wih, Whh, wp, fl);
  hipLaunchKernelGGL(prep_x, dim3(32768), dim3(256), 0, stream, x, xp);
  hipLaunchKernelGGL(lstm_main, dim3(256), dim3(256), 149504, stream,
                     wp, xp, hp, hf, fl, bih, bhh, Wfc, bfc, out);
}